// Round 15
// baseline (369.799 us; speedup 1.0000x reference)
//
#include <hip/hip_runtime.h>

#define IN_F   8192
#define OUT_F  14336
#define M_TOK  64
#define KPI    4096              // packed int32 per weight row
#define BN     64                // n per block (4 waves: 2x2 32x32 quadrants)
#define NBLK   (OUT_F / BN)      // 224
#define KSPLIT 16
#define KCHUNK (IN_F / KSPLIT)   // 512 k per block
#define BK     64                // k per staging step
#define NSTEP  (KCHUNK / BK)     // 8
#define XB_BLOCKS ((M_TOK * IN_F) / 4 / 256)   // 512
#define OI_BLOCKS ((M_TOK * OUT_F) / 4 / 256)  // 896

typedef __attribute__((ext_vector_type(8)))  short bf16x8;   // 8 bf16 (4 VGPRs)
typedef __attribute__((ext_vector_type(16))) float f32x16;   // 32x32 MFMA C/D frag

__device__ __forceinline__ unsigned short f2bf_rne(float f) {
    unsigned u = __builtin_bit_cast(unsigned, f);
    u += 0x7FFFu + ((u >> 16) & 1u);
    return (unsigned short)(u >> 16);
}

// Combined setup: blocks [0,512) convert x fp32 -> bf16; blocks [512,1408)
// initialize out[m][n] = bias[n] (gemm atomically accumulates into out).
__global__ __launch_bounds__(256) void qlin_setup(const float* __restrict__ x,
                                                  const float* __restrict__ bias,
                                                  unsigned short* __restrict__ xb,
                                                  float* __restrict__ out) {
    const int b   = blockIdx.x;
    const int tid = threadIdx.x;
    if (b < XB_BLOCKS) {
        int gid = b * 256 + tid;                       // 131072 float4
        float4 v = reinterpret_cast<const float4*>(x)[gid];
        ushort4 o;
        o.x = f2bf_rne(v.x);
        o.y = f2bf_rne(v.y);
        o.z = f2bf_rne(v.z);
        o.w = f2bf_rne(v.w);
        reinterpret_cast<ushort4*>(xb)[gid] = o;
    } else {
        int idx = (b - XB_BLOCKS) * 256 + tid;         // 0..229375 float4
        int nq  = idx % (OUT_F / 4);                   // compiler magic-div
        reinterpret_cast<float4*>(out)[idx] =
            reinterpret_cast<const float4*>(bias)[nq];
    }
}

// One packed int32 (byte: lo nibble = even k, hi nibble = odd k) -> two bf16
// bit-patterns in one dword. Ints in [-8,7] are exact in bf16.
__device__ __forceinline__ int unpack2_bf16(int v) {
    int q0 = ((int)((unsigned)v << 28)) >> 28;
    int q1 = ((int)((unsigned)v << 24)) >> 28;
    unsigned u0 = __builtin_bit_cast(unsigned, (float)q0);
    unsigned u1 = __builtin_bit_cast(unsigned, (float)q1);
    return (int)((u0 >> 16) | (u1 & 0xFFFF0000u));
}

__device__ __forceinline__ bf16x8 unpack_b(int4 wv) {
    int4 pk;
    pk.x = unpack2_bf16(wv.x);
    pk.y = unpack2_bf16(wv.y);
    pk.z = unpack2_bf16(wv.z);
    pk.w = unpack2_bf16(wv.w);
    return __builtin_bit_cast(bf16x8, pk);
}

// async 16-B global -> LDS (LDS dest = wave-uniform base + lane*16, fixed by HW).
__device__ __forceinline__ void gload_lds16(const void* g, void* l) {
    __builtin_amdgcn_global_load_lds(
        (const __attribute__((address_space(1))) unsigned int*)g,
        (__attribute__((address_space(3))) unsigned int*)l,
        16, 0, 0);
}

// Round-15: occupancy push #2 — x-LDS path removed, VGPR capped.
// R13/R14 gradient: 8 waves/CU=149us, ~16 waves/CU=~133us, all pipes idle
// => latency/queue-bound; more independent waves is the only lever that has
// measurably paid. R14 was likely VGPR-capped (R13: 88 VGPR; BN=64 => ~72,
// past the 64 cliff => 4 waves/SIMD). Changes:
//  - A-frags read DIRECTLY from global xb (R0-validated address math):
//    x is 1 MB, L2/L3-resident (total x traffic 229 MB ~= 7us chip-wide).
//    Removes 8 KB/step of gload_lds, 16 ds_reads/step, and halves LDS to
//    16 KB/2buf. Compiler inserts vmcnt waits at the MFMA uses of A-loads,
//    so the manual FIFO count for w-tiles stays valid.
//  - __launch_bounds__(256, 6): VGPR <= 84 (need ~65-70, no spill expected)
//    => 6 blocks = 24 waves/CU (LDS cap would be 10).
// Schedule unchanged (proven): 2-buffer, wait->barrier->COMPUTE->barrier->
// STAGE, counted vmcnt (w-stage = 2 instrs/wave => vmcnt(2)), never 0 in-loop.
__global__ __launch_bounds__(256, 6) void qlin_gemm(const unsigned short* __restrict__ xb,
                                                    const int* __restrict__ wp,
                                                    const float* __restrict__ scales,
                                                    float* __restrict__ out) {
    __shared__ int wlds[2][BN * (BK / 2)];   // 2 x 8 KB (w only; 16 KB total)

    const int tid  = threadIdx.x;
    const int wave = tid >> 6;
    const int lane = tid & 63;
    const int tp   = lane & 31;   // 32x32 frag: n (B) / m (A) / col (C)
    const int qp   = lane >> 5;   // 32x32 frag: k-half ; C/D row offset 4*qp
    const int nh   = wave & 1;    // n-half of this wave's 32x32 quadrant
    const int mh   = wave >> 1;   // m-half

    const int nblk = blockIdx.x % NBLK;
    const int kblk = blockIdx.x / NBLK;
    const int n0   = nblk * BN;
    const int kb   = kblk * KCHUNK;        // k base (elements)

    // this wave's x row base (A-frags stream straight from L2-resident xb)
    const unsigned short* xrow = xb + (size_t)(mh * 32 + tp) * IN_F + kb;

    f32x16 acc = {0.f,0.f,0.f,0.f,0.f,0.f,0.f,0.f,0.f,0.f,0.f,0.f,0.f,0.f,0.f,0.f};

    // ---- stage w-tile t into buffer b: 8 instrs per block (2/wave) ----
#define STAGE(b, t) do {                                                           \
    _Pragma("unroll")                                                              \
    for (int j = 0; j < 2; ++j) {                                                  \
        int li = (wave * 2 + j) * 64 + lane;       /* slot 0..511 */               \
        int r  = li >> 3;                          /* weight row 0..63 */          \
        int cg = (li & 7) ^ (r & 7);               /* global chunk (swizzled) */   \
        const int* gp = wp + (size_t)(n0 + r) * KPI + (kb >> 1) + (t) * (BK / 2) + cg * 4; \
        gload_lds16(gp, (char*)&wlds[b][0] + (size_t)li * 16);                     \
    }                                                                              \
} while (0)

#define COMPUTE(b, t) do {                                                         \
    _Pragma("unroll")                                                              \
    for (int kf = 0; kf < 4; ++kf) {                                               \
        const int c  = kf * 2 + qp;                /* 16-B chunk within row */     \
        const int Rn = nh * 32 + tp;               /* weight row of this wave */   \
        int4 wv = *reinterpret_cast<const int4*>(                                  \
            (const char*)&wlds[b][0] + (size_t)(Rn * 8 + (c ^ (Rn & 7))) * 16);    \
        bf16x8 bb = unpack_b(wv);                                                  \
        bf16x8 aa = *reinterpret_cast<const bf16x8*>(xrow + (t) * BK + c * 8);     \
        acc = __builtin_amdgcn_mfma_f32_32x32x16_bf16(aa, bb, acc, 0, 0, 0);       \
    }                                                                              \
} while (0)

    // prologue: 2-deep prefetch (4 w-gloads/wave in flight)
    STAGE(0, 0);
    STAGE(1, 1);

    for (int t = 0; t < NSTEP - 1; ++t) {
        const int cur = t & 1;
        // w-tile t landed when only tile t+1's 2 gloads remain outstanding.
        // (A-loads from the previous COMPUTE are already drained: the
        // compiler waits on each at its MFMA use, and they precede STAGE.)
        asm volatile("s_waitcnt vmcnt(2)" ::: "memory");
        __builtin_amdgcn_sched_barrier(0);
        __builtin_amdgcn_s_barrier();
        __builtin_amdgcn_sched_barrier(0);
        COMPUTE(cur, t);
        // every ds_read above is consumed by an MFMA before this barrier,
        // so after it buf[cur] is dead for all waves -> safe to overwrite.
        __builtin_amdgcn_sched_barrier(0);
        __builtin_amdgcn_s_barrier();
        __builtin_amdgcn_sched_barrier(0);
        if (t + 2 < NSTEP) STAGE(cur, t + 2);
    }
    // peeled final tile: its 2 gloads are the newest -> full drain
    asm volatile("s_waitcnt vmcnt(0)" ::: "memory");
    __builtin_amdgcn_sched_barrier(0);
    __builtin_amdgcn_s_barrier();
    __builtin_amdgcn_sched_barrier(0);
    COMPUTE((NSTEP - 1) & 1, NSTEP - 1);

    // ---- epilogue: C/D layout col=tp, row=(reg&3)+8*(reg>>2)+4*qp ----
    // out was pre-filled with bias; accumulate scale*acc with HW f32 atomics
    // (device-scope, order-independent across the 16 k-splits).
    const int   n  = n0 + nh * 32 + tp;
    const float sc = scales[n];
#pragma unroll
    for (int reg = 0; reg < 16; ++reg) {
        int m = mh * 32 + (reg & 3) + 8 * (reg >> 2) + 4 * qp;
        unsafeAtomicAdd(out + (size_t)m * OUT_F + n, acc[reg] * sc);
    }
#undef STAGE
#undef COMPUTE
}

extern "C" void kernel_launch(void* const* d_in, const int* in_sizes, int n_in,
                              void* d_out, int out_size, void* d_ws, size_t ws_size,
                              hipStream_t stream) {
    const float* x    = (const float*)d_in[0];
    const int*   wp   = (const int*)d_in[1];
    const float* sc   = (const float*)d_in[2];
    const float* bias = (const float*)d_in[3];
    float* out = (float*)d_out;

    unsigned short* xb = (unsigned short*)d_ws;   // 1 MB (only ws use)

    qlin_setup<<<XB_BLOCKS + OI_BLOCKS, 256, 0, stream>>>(x, bias, xb, out);
    qlin_gemm<<<NBLK * KSPLIT, 256, 0, stream>>>(xb, wp, sc, out);
}

// Round 19
// 341.872 us; speedup vs baseline: 1.0817x; 1.0817x over previous
//
#include <hip/hip_runtime.h>

#define IN_F   8192
#define OUT_F  14336
#define M_TOK  64
#define KPI    4096              // packed int32 per weight row
#define BN     64                // n per block (4 waves: 2x2 32x32 quadrants)
#define NBLK   (OUT_F / BN)      // 224
#define KSPLIT 16
#define KCHUNK (IN_F / KSPLIT)   // 512 k per block
#define BK     64                // k per staging step
#define NSTEP  (KCHUNK / BK)     // 8
#define XB_BLOCKS ((M_TOK * IN_F) / 4 / 256)   // 512
#define OI_BLOCKS ((M_TOK * OUT_F) / 4 / 256)  // 896

typedef __attribute__((ext_vector_type(8)))  short bf16x8;   // 8 bf16 (4 VGPRs)
typedef __attribute__((ext_vector_type(16))) float f32x16;   // 32x32 MFMA C/D frag

__device__ __forceinline__ unsigned short f2bf_rne(float f) {
    unsigned u = __builtin_bit_cast(unsigned, f);
    u += 0x7FFFu + ((u >> 16) & 1u);
    return (unsigned short)(u >> 16);
}

// Combined setup: blocks [0,512) convert x fp32 -> bf16; blocks [512,1408)
// initialize out[m][n] = bias[n] (gemm atomically accumulates into out).
__global__ __launch_bounds__(256) void qlin_setup(const float* __restrict__ x,
                                                  const float* __restrict__ bias,
                                                  unsigned short* __restrict__ xb,
                                                  float* __restrict__ out) {
    const int b   = blockIdx.x;
    const int tid = threadIdx.x;
    if (b < XB_BLOCKS) {
        int gid = b * 256 + tid;                       // 131072 float4
        float4 v = reinterpret_cast<const float4*>(x)[gid];
        ushort4 o;
        o.x = f2bf_rne(v.x);
        o.y = f2bf_rne(v.y);
        o.z = f2bf_rne(v.z);
        o.w = f2bf_rne(v.w);
        reinterpret_cast<ushort4*>(xb)[gid] = o;
    } else {
        int idx = (b - XB_BLOCKS) * 256 + tid;         // 0..229375 float4
        int nq  = idx % (OUT_F / 4);                   // compiler magic-div
        reinterpret_cast<float4*>(out)[idx] =
            reinterpret_cast<const float4*>(bias)[nq];
    }
}

// One packed int32 (byte: lo nibble = even k, hi nibble = odd k) -> two bf16
// bit-patterns in one dword. Ints in [-8,7] are exact in bf16.
__device__ __forceinline__ int unpack2_bf16(int v) {
    int q0 = ((int)((unsigned)v << 28)) >> 28;
    int q1 = ((int)((unsigned)v << 24)) >> 28;
    unsigned u0 = __builtin_bit_cast(unsigned, (float)q0);
    unsigned u1 = __builtin_bit_cast(unsigned, (float)q1);
    return (int)((u0 >> 16) | (u1 & 0xFFFF0000u));
}

__device__ __forceinline__ bf16x8 unpack_b(int4 wv) {
    int4 pk;
    pk.x = unpack2_bf16(wv.x);
    pk.y = unpack2_bf16(wv.y);
    pk.z = unpack2_bf16(wv.z);
    pk.w = unpack2_bf16(wv.w);
    return __builtin_bit_cast(bf16x8, pk);
}

// async 16-B global -> LDS (LDS dest = wave-uniform base + lane*16, fixed by HW).
__device__ __forceinline__ void gload_lds16(const void* g, void* l) {
    __builtin_amdgcn_global_load_lds(
        (const __attribute__((address_space(1))) unsigned int*)g,
        (__attribute__((address_space(3))) unsigned int*)l,
        16, 0, 0);
}

// Round-16: R15's x-direct A-loads regressed 340->370 exactly as the R0
// pathology predicted (16 KB lane stride => 32-line scatter => L1 thrash):
// x-LDS staging is load-bearing. This round = R14 (measured best, 340.2)
// + ONE change: __launch_bounds__(256, 8) to force VGPR <= 64.
// R14 audit: LDS 32 KB caps 5 blocks/CU but VGPR ~72 sits past the 64-VGPR
// occupancy cliff (waves/SIMD halve at 64/128/256) => R14 ran 4 blocks/CU
// VGPR-capped. Cap at 64 => 5 blocks = 20 waves/CU (+25% independent
// pipelines), following the measured occupancy gradient (8w=149us, 16w=133us,
// all pipes idle => latency/queue-bound). If the allocator spills to reach
// 64, gemm regresses >150 and we revert to R14 verbatim as the floor.
__global__ __launch_bounds__(256, 8) void qlin_gemm(const unsigned short* __restrict__ xb,
                                                    const int* __restrict__ wp,
                                                    const float* __restrict__ scales,
                                                    float* __restrict__ out) {
    __shared__ int            wlds[2][BN * (BK / 2)];   // 2 x 8 KB
    __shared__ unsigned short xlds[2][M_TOK * BK];      // 2 x 8 KB  (32 KB total)

    const int tid  = threadIdx.x;
    const int wave = tid >> 6;
    const int lane = tid & 63;
    const int tp   = lane & 31;   // 32x32 frag: n (B) / m (A) / col (C)
    const int qp   = lane >> 5;   // 32x32 frag: k-half ; C/D row offset 4*qp
    const int nh   = wave & 1;    // n-half of this wave's 32x32 quadrant
    const int mh   = wave >> 1;   // m-half

    const int nblk = blockIdx.x % NBLK;
    const int kblk = blockIdx.x / NBLK;
    const int n0   = nblk * BN;
    const int kb   = kblk * KCHUNK;        // k base (elements)

    f32x16 acc = {0.f,0.f,0.f,0.f,0.f,0.f,0.f,0.f,0.f,0.f,0.f,0.f,0.f,0.f,0.f,0.f};

    // ---- stage tile t into buffer b: 8 instrs w + 8 instrs x per block ----
#define STAGE(b, t) do {                                                           \
    _Pragma("unroll")                                                              \
    for (int j = 0; j < 2; ++j) {                                                  \
        int li = (wave * 2 + j) * 64 + lane;       /* slot 0..511 */               \
        int r  = li >> 3;                          /* weight row 0..63 */          \
        int cg = (li & 7) ^ (r & 7);               /* global chunk (swizzled) */   \
        const int* gp = wp + (size_t)(n0 + r) * KPI + (kb >> 1) + (t) * (BK / 2) + cg * 4; \
        gload_lds16(gp, (char*)&wlds[b][0] + (size_t)li * 16);                     \
    }                                                                              \
    _Pragma("unroll")                                                              \
    for (int j = 0; j < 2; ++j) {                                                  \
        int li = (wave * 2 + j) * 64 + lane;       /* slot 0..511 */               \
        int r  = li >> 3;                          /* m row 0..63 */               \
        int cg = (li & 7) ^ (r & 7);                                               \
        const unsigned short* gp = xb + (size_t)r * IN_F + kb + (t) * BK + cg * 8; \
        gload_lds16(gp, (char*)&xlds[b][0] + (size_t)li * 16);                     \
    }                                                                              \
} while (0)

#define COMPUTE(b) do {                                                            \
    _Pragma("unroll")                                                              \
    for (int kf = 0; kf < 4; ++kf) {                                               \
        const int c  = kf * 2 + qp;                /* 16-B chunk within row */     \
        const int Rn = nh * 32 + tp;               /* weight row of this wave */   \
        const int Rm = mh * 32 + tp;               /* x row of this wave */        \
        int4 wv = *reinterpret_cast<const int4*>(                                  \
            (const char*)&wlds[b][0] + (size_t)(Rn * 8 + (c ^ (Rn & 7))) * 16);    \
        bf16x8 bb = unpack_b(wv);                                                  \
        bf16x8 aa = *reinterpret_cast<const bf16x8*>(                              \
            (const char*)&xlds[b][0] + (size_t)(Rm * 8 + (c ^ (Rm & 7))) * 16);    \
        acc = __builtin_amdgcn_mfma_f32_32x32x16_bf16(aa, bb, acc, 0, 0, 0);       \
    }                                                                              \
} while (0)

    // prologue: 2-deep prefetch (8 vmem ops/wave in flight)
    STAGE(0, 0);
    STAGE(1, 1);

    for (int t = 0; t < NSTEP - 1; ++t) {
        const int cur = t & 1;
        // tile t complete when only tile t+1's 4 ops remain outstanding
        asm volatile("s_waitcnt vmcnt(4)" ::: "memory");
        __builtin_amdgcn_sched_barrier(0);
        __builtin_amdgcn_s_barrier();
        __builtin_amdgcn_sched_barrier(0);
        COMPUTE(cur);
        // every ds_read above is consumed by an MFMA before this barrier,
        // so after it buf[cur] is dead for all waves -> safe to overwrite.
        __builtin_amdgcn_sched_barrier(0);
        __builtin_amdgcn_s_barrier();
        __builtin_amdgcn_sched_barrier(0);
        if (t + 2 < NSTEP) STAGE(cur, t + 2);
    }
    // peeled final tile: its 4 ops are the newest -> full drain
    asm volatile("s_waitcnt vmcnt(0)" ::: "memory");
    __builtin_amdgcn_sched_barrier(0);
    __builtin_amdgcn_s_barrier();
    __builtin_amdgcn_sched_barrier(0);
    COMPUTE((NSTEP - 1) & 1);

    // ---- epilogue: C/D layout col=tp, row=(reg&3)+8*(reg>>2)+4*qp ----
    // out was pre-filled with bias; accumulate scale*acc with HW f32 atomics
    // (device-scope, order-independent across the 16 k-splits).
    const int   n  = n0 + nh * 32 + tp;
    const float sc = scales[n];
#pragma unroll
    for (int reg = 0; reg < 16; ++reg) {
        int m = mh * 32 + (reg & 3) + 8 * (reg >> 2) + 4 * qp;
        unsafeAtomicAdd(out + (size_t)m * OUT_F + n, acc[reg] * sc);
    }
#undef STAGE
#undef COMPUTE
}

extern "C" void kernel_launch(void* const* d_in, const int* in_sizes, int n_in,
                              void* d_out, int out_size, void* d_ws, size_t ws_size,
                              hipStream_t stream) {
    const float* x    = (const float*)d_in[0];
    const int*   wp   = (const int*)d_in[1];
    const float* sc   = (const float*)d_in[2];
    const float* bias = (const float*)d_in[3];
    float* out = (float*)d_out;

    unsigned short* xb = (unsigned short*)d_ws;   // 1 MB (only ws use)

    qlin_setup<<<XB_BLOCKS + OI_BLOCKS, 256, 0, stream>>>(x, bias, xb, out);
    qlin_gemm<<<NBLK * KSPLIT, 256, 0, stream>>>(xb, wp, sc, out);
}